// Round 8
// baseline (239.970 us; speedup 1.0000x reference)
//
#include <hip/hip_runtime.h>

// SSIM-like loss, factored form:
//   term_n uses 3^n * (ZrV)^(n+1) (ZcH)^(n+1) (channel_sum): ONE vertical and ONE
//   horizontal (2h+1)-tap conv with exact edge-clipped weight rows (compile-time
//   __constant__ table). 32x32 output tile, 48x48 window.
//   R7 (resubmit; previous round was an infra failure, no counters): CROSS-TILE
//   PIPELINED BLOCKS. Each block runs 4 tiles (2 of sample p, 2 of sample 7-p ->
//   identical work for EVERY block; T-sums pair-balanced) with LDS double-buffer:
//   loads for tile g+1 are issued to regs before tile g's compute and written to
//   the other buffer under H/V compute cover -> global latency explicitly hidden
//   (stagger/implicit overlap proved null in R6). Staging is H-independent (full
//   window) so prefetch crosses the H boundary. LDS 39,784 B -> 4 blocks/CU;
//   __launch_bounds__(256,4) -> 128-VGPR budget (R1 lesson: too-tight bounds
//   spill catastrophically; WRITE_SIZE is the spill tripwire).
//   Grid 2048 = 2 generations of 4/CU. One reduce+store per 2 tiles.

typedef float v2f __attribute__((ext_vector_type(2)));
typedef float v4f __attribute__((ext_vector_type(4)));

#define BSTR 50     // buf float2 stride (even -> 16B-aligned rows for b128)
#define PC 0.19487473f
#define QC 0.23021731f
#define NSLOT 512   // store slots per sample: h*256 + jj

// ---- compile-time clipped 1-D weight rows: w[H-1][d*T + k], T = 2H+1,
//      d = dist to edge (0..H-1), d = H = interior row.
struct WtTables { float w[8][153]; };
static constexpr WtTables make_tables() {
  WtTables t{};
  for (int H = 1; H <= 8; ++H) {
    const int T = 2 * H + 1;
    for (int d = 0; d <= H; ++d) {
      float Wd[17] = {};
      for (int k = 0; k < T; ++k) Wd[k] = (k == H) ? 1.f : 0.f;
      const int kmin = H - d;
      for (int m = 0; m < H; ++m) {
        float prev = 0.f;
        for (int k = kmin; k < T; ++k) {
          const float cur = Wd[k];
          const float nxt = (k < T - 1) ? Wd[k + 1] : 0.f;
          Wd[k] = QC * cur + PC * (prev + nxt);
          prev = cur;
        }
      }
      for (int k = 0; k < T; ++k) t.w[H - 1][d * T + k] = Wd[k];
    }
  }
  return t;
}
__constant__ WtTables WTAB = make_tables();

struct SharedMem {
  v2f buf[2][48 * BSTR];  // 38,400 B  double-buffered window
  double wred[4 * 5];     //    160 B  per-wave partials
  float Wt[2][153];       //  1,224 B  clipped rows for both H values of this block
};                        // 39,784 B -> 40,960 granule -> 4 blocks/CU

__global__ __launch_bounds__(256) void ssim_zero(double* acc) {
  for (int i = threadIdx.x; i < 8 * 64 * 5; i += 256) acc[i] = 0.0;
}

// ---- one staging cell: full 48x48 window (H-independent), 6 v4f in flight,
//      channel-sum + (A,B)-interleave in regs, 2 pure b128 LDS writes.
struct Stage {
  v4f x0, x1, x2, y0, y1, y2;
  int row, c4;
  bool ok;
  __device__ __forceinline__ void issue(const float* __restrict__ xp,
                                        const float* __restrict__ yp,
                                        size_t base, int oy, int ox, int cell) {
    row = cell / 12;
    c4 = cell - row * 12;
    const int gy = oy + row - 8, gx = ox + c4 * 4 - 8;
    ok = ((unsigned)gy < 1024u) & ((unsigned)gx < 1024u);
    if (ok) {
      const size_t off = base + (size_t)gy * 1024u + (unsigned)gx;
      const v4f* px = (const v4f*)(xp + off);
      const v4f* py = (const v4f*)(yp + off);
      x0 = px[0];      y0 = py[0];
      x1 = px[262144]; y1 = py[262144];   // +1 channel (1024*1024 floats)
      x2 = px[524288]; y2 = py[524288];
    }
  }
  __device__ __forceinline__ void write(v2f* buf) {
    v4f sx = {0.f, 0.f, 0.f, 0.f}, sy = {0.f, 0.f, 0.f, 0.f};
    if (ok) { sx = x0 + x1 + x2; sy = y0 + y1 + y2; }
    v4f* d = (v4f*)(buf + row * BSTR + c4 * 4);
    d[0] = (v4f){sx.x, sy.x, sx.y, sy.y};
    d[1] = (v4f){sx.z, sy.z, sx.w, sy.w};
  }
};

__device__ __forceinline__ void stage_full(v2f* buf, const float* __restrict__ xp,
                                           const float* __restrict__ yp,
                                           int n0, int tile) {
  const int tid = threadIdx.x;
  const size_t base = (size_t)n0 * 3145728u;
  const int oy = (tile >> 5) * 32, ox = (tile & 31) * 32;
  Stage a, b, c;
  a.issue(xp, yp, base, oy, ox, tid);
  b.issue(xp, yp, base, oy, ox, tid + 256);
  a.write(buf);
  b.write(buf);
  if (tid < 64) { c.issue(xp, yp, base, oy, ox, tid + 512); c.write(buf); }
}

// ---- one tile: compute from buf[cur]; stage next tile into buf[cur^1] under
//      compute cover (issue early, write late). 3 barriers/tile.
template <int H>
__device__ __forceinline__ void compute_tile(
    SharedMem& sm, const int cur, const int hi, const int tile,
    const bool hasNext, const int n2, const int tile2,
    const float* __restrict__ xp, const float* __restrict__ yp, float (&s5)[5]) {
  constexpr int T = 2 * H + 1;
  constexpr int n = H - 1;
  constexpr int R0 = 8 - H, R1 = 39 + H;
  const int tid = threadIdx.x;
  const int tr = tile >> 5, tc = tile & 31;
  const int oy = tr * 32, ox = tc * 32;
  const bool rowEdge = (tr == 0) | (tr == 31);
  const bool colEdge = (tc == 0) | (tc == 31);
  v2f* bufc = sm.buf[cur];
  v2f* bufn = sm.buf[cur ^ 1];
  const int oy2 = (tile2 >> 5) * 32, ox2 = (tile2 & 31) * 32;
  const size_t base2 = (size_t)n2 * 3145728u;

  Stage stA, stB, stC;
  if (hasNext) stA.issue(xp, yp, base2, oy2, ox2, tid);   // in flight across barrier

  __syncthreads();   // [1] this tile's staged data (and Wt) visible

  // ---- H pass: wave cg owns 8 out cols, lane = window row ----
  const int cg = tid >> 6;
  const int i0 = tid & 63;
  constexpr int I0 = (8 - H) >> 1, I1 = (15 + H) >> 1;
  const bool val = (i0 >= R0) & (i0 <= R1);
  v2f o[8] = {};
  if (val) {
    const v4f* s4 = (const v4f*)(bufc + i0 * BSTR + cg * 8);
    v2f win[24];
#pragma unroll
    for (int i = I0; i <= I1; ++i) {
      const v4f t = s4[i];
      win[2 * i] = (v2f){t.x, t.y};
      win[2 * i + 1] = (v2f){t.z, t.w};
    }
    if (!colEdge) {
#pragma unroll
      for (int k = 0; k < T; ++k) {
        const float cw = WTAB.w[n][H * T + k];   // compile-time-constant index
#pragma unroll
        for (int j = 0; j < 8; ++j) o[j] += cw * win[j + k + 8 - H];
      }
    } else {
      int A0[8], sg[8];
#pragma unroll
      for (int j = 0; j < 8; ++j) {
        const int gx = ox + cg * 8 + j;
        int dd = H, rv = 0;
        if (gx < H) dd = gx;
        else if (gx > 1023 - H) { dd = 1023 - gx; rv = 1; }
        A0[j] = dd * T + (rv ? 2 * H : 0);
        sg[j] = rv ? -1 : 1;
      }
#pragma unroll
      for (int j = 0; j < 8; ++j)
        for (int k = 0; k < T; ++k)
          o[j] += sm.Wt[hi][A0[j] + sg[j] * k] * win[j + k + 8 - H];
    }
  }
  if (hasNext) {                      // A's vmcnt covered by H pass; B goes in flight
    stA.write(bufn);
    stB.issue(xp, yp, base2, oy2, ox2, tid + 256);
  }
  __syncthreads();   // [2] all H reads done before in-place write
  if (val) {
    v4f* d = (v4f*)(bufc + i0 * BSTR + cg * 8 + 8);
#pragma unroll
    for (int q = 0; q < 4; ++q)
      d[q] = (v4f){o[2 * q].x, o[2 * q].y, o[2 * q + 1].x, o[2 * q + 1].y};
  }
  __syncthreads();   // [3]

  // ---- V pass + fp32 moments: 4 contiguous rows/thread ----
  {
    const int jt = tid & 31;
    const int iv = tid >> 5;
    constexpr int C0 = 8 - H, C1 = 11 + H;
    v2f vwin[20];
#pragma unroll
    for (int c = C0; c <= C1; ++c)
      vwin[c] = bufc[(4 * iv + c) * BSTR + 8 + jt];
    v2f o2[4] = {};
    if (!rowEdge) {
#pragma unroll
      for (int k = 0; k < T; ++k) {
        const float cw = WTAB.w[n][H * T + k];
#pragma unroll
        for (int rr = 0; rr < 4; ++rr) o2[rr] += cw * vwin[rr + k + 8 - H];
      }
    } else {
#pragma unroll
      for (int rr = 0; rr < 4; ++rr) {
        const int gy = oy + 4 * iv + rr;
        int dd = H, rv = 0;
        if (gy < H) dd = gy;
        else if (gy > 1023 - H) { dd = 1023 - gy; rv = 1; }
        const int A0 = dd * T + (rv ? 2 * H : 0);
        const int sg2 = rv ? -1 : 1;
        for (int k = 0; k < T; ++k)
          o2[rr] += sm.Wt[hi][A0 + sg2 * k] * vwin[rr + k + 8 - H];
      }
    }
    constexpr float scales[8] = {1.f, 3.f, 9.f, 27.f, 81.f, 243.f, 729.f, 2187.f};
    constexpr float scale = scales[n];
#pragma unroll
    for (int rr = 0; rr < 4; ++rr) {
      const float A = scale * o2[rr].x;
      const float B = scale * o2[rr].y;
      s5[0] += A; s5[1] += B;
      s5[2] += A * A; s5[3] += B * B; s5[4] += A * B;
    }
  }
  if (hasNext) {                      // B's vmcnt covered by H-write + V pass
    stB.write(bufn);
    if (tid < 64) { stC.issue(xp, yp, base2, oy2, ox2, tid + 512); stC.write(bufn); }
  }
  // no trailing barrier: next tile's [1] provides it
}

__device__ __forceinline__ void reduceStore(SharedMem& sm, const float (&s5)[5],
                                            double* __restrict__ acc, int n0,
                                            int slot, int useStore) {
  double v[5];
#pragma unroll
  for (int k = 0; k < 5; ++k) v[k] = (double)s5[k];
#pragma unroll
  for (int off = 32; off > 0; off >>= 1) {
#pragma unroll
    for (int k = 0; k < 5; ++k) v[k] += __shfl_down(v[k], off, 64);
  }
  const int tid = threadIdx.x, lane = tid & 63, wv = tid >> 6;
  if (lane == 0) {
#pragma unroll
    for (int k = 0; k < 5; ++k) sm.wred[wv * 5 + k] = v[k];
  }
  __syncthreads();
  if (tid == 0) {
    if (useStore) {
      double* an = acc + (size_t)(n0 * NSLOT + slot) * 5;
#pragma unroll
      for (int k = 0; k < 5; ++k)
        an[k] = sm.wred[k] + sm.wred[5 + k] + sm.wred[10 + k] + sm.wred[15 + k];
    } else {
      double* an = acc + (size_t)(n0 * 64 + (slot & 63)) * 5;
#pragma unroll
      for (int k = 0; k < 5; ++k)
        atomicAdd(&an[k], sm.wred[k] + sm.wred[5 + k] + sm.wred[10 + k] + sm.wred[15 + k]);
    }
  }
  __syncthreads();   // wred reused by the second reduce
}

// Block = 4 tiles: g0,g1 on sample p (H=HA), g2,g3 on sample 7-p (H=HB).
// tiles: g0:(p,T0) g1:(p,T1) g2:(7-p,T0) g3:(7-p,T1); T0=h*512+jj, T1=T0+256.
template <int HA, int HB>
__device__ __forceinline__ void runBlock(SharedMem& sm, int h, int jj,
                                         const float* __restrict__ xp,
                                         const float* __restrict__ yp,
                                         double* __restrict__ acc, int useStore) {
  constexpr int nA = HA - 1, nB = HB - 1;
  const int T0 = h * 512 + jj;
  const int T1 = T0 + 256;
  stage_full(sm.buf[0], xp, yp, nA, T0);

  float s5[5] = {0.f, 0.f, 0.f, 0.f, 0.f};
  compute_tile<HA>(sm, 0, 0, T0, true, nA, T1, xp, yp, s5);
  compute_tile<HA>(sm, 1, 0, T1, true, nB, T0, xp, yp, s5);
  reduceStore(sm, s5, acc, nA, h * 256 + jj, useStore);
#pragma unroll
  for (int k = 0; k < 5; ++k) s5[k] = 0.f;
  compute_tile<HB>(sm, 0, 1, T0, true, nB, T1, xp, yp, s5);
  compute_tile<HB>(sm, 1, 1, T1, false, 0, 0, xp, yp, s5);
  reduceStore(sm, s5, acc, nB, h * 256 + jj, useStore);
}

__global__ __launch_bounds__(256, 4) void ssim_main(const float* __restrict__ xp,
                                                    const float* __restrict__ yp,
                                                    double* __restrict__ acc,
                                                    int useStore) {
  __shared__ SharedMem sm;
  const int bid = blockIdx.x;            // 0..2047
  const int xcd = bid & 7;               // round-robin -> XCD; pair (p,7-p) per XCD
  const int jj = bid >> 3;               // 0..255
  const int p = xcd >> 1;
  const int h = xcd & 1;
  for (int i = threadIdx.x; i < 153; i += 256) {
    sm.Wt[0][i] = WTAB.w[p][i];
    sm.Wt[1][i] = WTAB.w[7 - p][i];
  }
  switch (p) {
    case 0:  runBlock<1, 8>(sm, h, jj, xp, yp, acc, useStore); break;
    case 1:  runBlock<2, 7>(sm, h, jj, xp, yp, acc, useStore); break;
    case 2:  runBlock<3, 6>(sm, h, jj, xp, yp, acc, useStore); break;
    default: runBlock<4, 5>(sm, h, jj, xp, yp, acc, useStore); break;
  }
}

__global__ __launch_bounds__(1024) void ssim_final(const double* __restrict__ acc,
                                                   float* __restrict__ out, int nslot) {
  // 1024 threads = 8 samples x 128 lanes; lane l sums slots l, l+128, ...
  __shared__ double wp[16][5];
  __shared__ double terms[8];
  const int tid = threadIdx.x;
  const int s = tid >> 7;
  const int l = tid & 127;
  double v[5] = {0.0, 0.0, 0.0, 0.0, 0.0};
  for (int slot = l; slot < nslot; slot += 128) {
    const double* p = acc + (size_t)(s * nslot + slot) * 5;
#pragma unroll
    for (int k = 0; k < 5; ++k) v[k] += p[k];
  }
#pragma unroll
  for (int off = 32; off > 0; off >>= 1) {
#pragma unroll
    for (int k = 0; k < 5; ++k) v[k] += __shfl_down(v[k], off, 64);
  }
  if ((tid & 63) == 0) {
#pragma unroll
    for (int k = 0; k < 5; ++k) wp[tid >> 6][k] = v[k];
  }
  __syncthreads();
  if (tid < 8) {
    double u[5];
#pragma unroll
    for (int k = 0; k < 5; ++k) u[k] = wp[2 * tid][k] + wp[2 * tid + 1][k];
    const double C1 = 6.5025;     // (0.01*255)^2
    const double C2 = 58.5225;    // (0.03*255)^2
    const double N = 1048576.0;
    const double mA = u[0] / N, mB = u[1] / N;
    const double varA = (u[2] - N * mA * mA) / (N - 1.0);
    const double varB = (u[3] - N * mB * mB) / (N - 1.0);
    const double cov  = (u[4] - N * mA * mB) / (N - 1.0);
    terms[tid] = ((2.0 * mA * mB + C1) * (2.0 * cov + C2)) /
                 ((mA * mA + mB * mB + C1) * (varA * varA + varB * varB + C2));
  }
  __syncthreads();
  if (tid == 0) {
    double tot = 0.0;
    for (int i = 0; i < 8; ++i) tot += terms[i];
    out[0] = (float)tot;
  }
}

extern "C" void kernel_launch(void* const* d_in, const int* in_sizes, int n_in,
                              void* d_out, int out_size, void* d_ws, size_t ws_size,
                              hipStream_t stream) {
  const float* x = (const float*)d_in[0];
  const float* y = (const float*)d_in[1];
  double* acc = (double*)d_ws;
  float* out = (float*)d_out;

  // Per-block private slots (no zeroing, no atomics) if the workspace allows:
  const size_t need = (size_t)8 * NSLOT * 5 * sizeof(double);   // 160 KB
  const int bigws = ws_size >= need;

  if (!bigws) ssim_zero<<<1, 256, 0, stream>>>(acc);
  ssim_main<<<2048, 256, 0, stream>>>(x, y, acc, bigws);
  ssim_final<<<1, 1024, 0, stream>>>(acc, out, bigws ? NSLOT : 64);
}